// Round 13
// baseline (663.005 us; speedup 1.0000x reference)
//
#include <hip/hip_runtime.h>
#include <math.h>

typedef unsigned short u16;
typedef unsigned int u32;
typedef __attribute__((ext_vector_type(8))) short short8;
typedef __attribute__((ext_vector_type(4))) float f32x4;
typedef __attribute__((ext_vector_type(16))) float f32x16;
typedef __attribute__((ext_vector_type(4))) u32 u32x4;
typedef __attribute__((ext_vector_type(2))) u32 u32x2;

#define DEVFN static __device__ __forceinline__

DEVFN u16 f2bf(float x) {
  union { float f; u32 u; } v; v.f = x;
  u32 r = v.u + 0x7fffu + ((v.u >> 16) & 1u);
  return (u16)(r >> 16);
}
DEVFN float bf2f(u16 h) {
  union { u32 u; float f; } v; v.u = ((u32)h) << 16;
  return v.f;
}
DEVFN u32 packbf2(float a, float b) {
  return (u32)f2bf(a) | ((u32)f2bf(b) << 16);
}
DEVFN void gl2lds16(const u16* g, u16* l) {
  __builtin_amdgcn_global_load_lds(
      (const __attribute__((address_space(1))) u32*)g,
      (__attribute__((address_space(3))) u32*)l, 16, 0, 0);
}
// exact GELU via A&S 7.1.26 erf approx (|eps|<=1.5e-7)
DEVFN float gelu_exact(float v) {
  float s = v * 0.70710678118654752f;
  float ax = fabsf(s);
  float t = __builtin_amdgcn_rcpf(1.0f + 0.3275911f * ax);
  float poly = t * (0.254829592f +
               t * (-0.284496736f +
               t * (1.421413741f +
               t * (-1.453152027f + t * 1.061405429f))));
  float e = __expf(-s * s);
  float er = 1.0f - poly * e;
  er = (s < 0.f) ? -er : er;
  return 0.5f * v * (1.0f + er);
}

#define VMW4() asm volatile("s_waitcnt vmcnt(4)" ::: "memory")
#define VMW2() asm volatile("s_waitcnt vmcnt(2)" ::: "memory")
#define VMW0() asm volatile("s_waitcnt vmcnt(0)" ::: "memory")
#define CFENCE() asm volatile("" ::: "memory")
#define BARRIER() do { CFENCE(); __builtin_amdgcn_s_barrier(); CFENCE(); } while (0)

// ---------------- fused: transpose+convert all 6 weights  AND  ln1.
// blocks [0,16384): wq/wk/wv/wo  [16384,32768): w1  [32768,49152): w2
// blocks [49152,53248): ln1 rows (one block per row of x)
__global__ __launch_bounds__(256) void tconvln_k(
    const float* __restrict__ wq, const float* __restrict__ wk,
    const float* __restrict__ wv, const float* __restrict__ wo,
    const float* __restrict__ w1, const float* __restrict__ w2,
    u16* __restrict__ wqt, u16* __restrict__ wkt, u16* __restrict__ wvt,
    u16* __restrict__ wot, u16* __restrict__ w1t, u16* __restrict__ w2t,
    const float* __restrict__ x, const float* __restrict__ ln1w,
    const float* __restrict__ ln1b, float* __restrict__ y32,
    u16* __restrict__ y16) {
  int b = blockIdx.x;
  int t = threadIdx.x;
  if (b >= 49152) {  // ---- ln1 row
    long base = (long)(b - 49152) * 2048;
    float4 v0 = ((const float4*)(x + base))[2 * t];
    float4 v1 = ((const float4*)(x + base))[2 * t + 1];
    float xv[8];
    *(float4*)xv = v0; *(float4*)(xv + 4) = v1;
    float s = 0.f, ss = 0.f;
#pragma unroll
    for (int i = 0; i < 8; ++i) { s += xv[i]; ss += xv[i] * xv[i]; }
#pragma unroll
    for (int m = 1; m < 64; m <<= 1) { s += __shfl_xor(s, m); ss += __shfl_xor(ss, m); }
    __shared__ float rs[4], rss[4];
    int wave = t >> 6;
    if ((t & 63) == 0) { rs[wave] = s; rss[wave] = ss; }
    __syncthreads();
    s = rs[0] + rs[1] + rs[2] + rs[3];
    ss = rss[0] + rss[1] + rss[2] + rss[3];
    float mean = s * (1.f / 2048.f);
    float var = ss * (1.f / 2048.f) - mean * mean;
    float inv = rsqrtf(var + 1e-5f);
    float wv8[8], bv[8];
    *(float4*)wv8 = ((const float4*)ln1w)[2 * t];
    *(float4*)(wv8 + 4) = ((const float4*)ln1w)[2 * t + 1];
    *(float4*)bv = ((const float4*)ln1b)[2 * t];
    *(float4*)(bv + 4) = ((const float4*)ln1b)[2 * t + 1];
    float yv[8];
#pragma unroll
    for (int i = 0; i < 8; ++i) yv[i] = (xv[i] - mean) * inv * wv8[i] + bv[i];
    ((float4*)(y32 + base))[2 * t] = *(float4*)yv;
    ((float4*)(y32 + base))[2 * t + 1] = *(float4*)(yv + 4);
    u32x4 ov;
#pragma unroll
    for (int i = 0; i < 4; ++i) ov[i] = packbf2(yv[2 * i], yv[2 * i + 1]);
    ((u32x4*)(y16 + base))[t] = ov;
    return;
  }
  // ---- weight transpose tile
  __shared__ float tile[32][33];
  const float* in; u16* out; int K, N, tn, tk;
  if (b < 16384) {
    int wsel = b >> 12;
    int loc = b & 4095;
    in = (wsel == 0) ? wq : (wsel == 1) ? wk : (wsel == 2) ? wv : wo;
    out = (wsel == 0) ? wqt : (wsel == 1) ? wkt : (wsel == 2) ? wvt : wot;
    K = 2048; N = 2048; tn = loc & 63; tk = loc >> 6;
  } else if (b < 32768) {
    int loc = b - 16384; in = w1; out = w1t; K = 2048; N = 8192;
    tn = loc & 255; tk = loc >> 8;
  } else {
    int loc = b - 32768; in = w2; out = w2t; K = 8192; N = 2048;
    tn = loc & 63; tk = loc >> 6;
  }
  int n0 = tn << 5, k0 = tk << 5;
  int tx = t & 31, ty = t >> 5;
#pragma unroll
  for (int i = 0; i < 32; i += 8)
    tile[ty + i][tx] = in[(long)(k0 + ty + i) * N + n0 + tx];
  __syncthreads();
#pragma unroll
  for (int i = 0; i < 32; i += 8)
    out[(long)(n0 + ty + i) * K + k0 + tx] = f2bf(tile[tx][ty + i]);
}

// ---------------- LayerNorm (bf16 in) -> bf16 out.
__global__ __launch_bounds__(256) void ln2_k(const u16* __restrict__ a,
                                             const float* __restrict__ w,
                                             const float* __restrict__ b,
                                             u16* __restrict__ y) {
  long base = (long)blockIdx.x * 2048;
  int t = threadIdx.x;
  u32x4 pv = ((const u32x4*)(a + base))[t];
  float xv[8];
#pragma unroll
  for (int i = 0; i < 4; ++i) {
    xv[2 * i] = bf2f((u16)(pv[i] & 0xffffu));
    xv[2 * i + 1] = bf2f((u16)(pv[i] >> 16));
  }
  float s = 0.f, ss = 0.f;
#pragma unroll
  for (int i = 0; i < 8; ++i) { s += xv[i]; ss += xv[i] * xv[i]; }
#pragma unroll
  for (int m = 1; m < 64; m <<= 1) { s += __shfl_xor(s, m); ss += __shfl_xor(ss, m); }
  __shared__ float rs[4], rss[4];
  int wave = t >> 6;
  if ((t & 63) == 0) { rs[wave] = s; rss[wave] = ss; }
  __syncthreads();
  s = rs[0] + rs[1] + rs[2] + rs[3];
  ss = rss[0] + rss[1] + rss[2] + rss[3];
  float mean = s * (1.f / 2048.f);
  float var = ss * (1.f / 2048.f) - mean * mean;
  float inv = rsqrtf(var + 1e-5f);
  float wv[8], bv[8];
  *(float4*)wv = ((const float4*)w)[2 * t]; *(float4*)(wv + 4) = ((const float4*)w)[2 * t + 1];
  *(float4*)bv = ((const float4*)b)[2 * t]; *(float4*)(bv + 4) = ((const float4*)b)[2 * t + 1];
  u32x4 ov;
#pragma unroll
  for (int i = 0; i < 4; ++i) {
    float y0 = (xv[2 * i] - mean) * inv * wv[2 * i] + bv[2 * i];
    float y1 = (xv[2 * i + 1] - mean) * inv * wv[2 * i + 1] + bv[2 * i + 1];
    ov[i] = packbf2(y0, y1);
  }
  ((u32x4*)(y + base))[t] = ov;
}

// =====================================================================
// Phase-scheduled GEMM (r3 engine — measured best: 0 conflicts).
// 512 threads = 8 waves (2M x 4N). BK=64. BN=256.
// IM=8 -> BM=256 (4 phases), IM=4 -> BM=128 (2 phases).
// Per-round cost ~1.28 us/K-tile (measured r3): IM=4 K=2048 1-round = 41us.
// MODE 0: fused QKV (W=[6144,2048]) -> q/k [B,H,S,D], v [B,H,D,S]
// MODE 2: +bias+resid(f32) -> bf16   MODE 3: +bias, exact GELU -> bf16
// MODE 4: +bias+resid(f32) -> f32
// =====================================================================
template <int MODE, int IM>
__global__ __launch_bounds__(512, 2) void gemm8_k(const u16* __restrict__ A,
                                                  const u16* __restrict__ W,
                                                  void* __restrict__ outp,
                                                  const float* __restrict__ bias,
                                                  const float* __restrict__ resid,
                                                  int M, int N, int K) {
  constexpr int BM = IM * 32;  // 256 or 128
  constexpr int BN = 256;
  __shared__ __align__(16) u16 lds[2][(BM + BN) * 64];
  const int t = threadIdx.x, lane = t & 63, wave = t >> 6;
  const int g = lane >> 4, r16 = lane & 15;
  const int wm = wave >> 2, wn = wave & 3;
  const int nM = M / BM;
  const int nwg = gridDim.x * gridDim.y;
  const int orig = blockIdx.y * gridDim.x + blockIdx.x;
  const int sw = (nwg & 7) ? orig : ((orig & 7) * (nwg >> 3) + (orig >> 3));
  const long m0 = (long)(sw % nM) * BM, n0 = (long)(sw / nM) * BN;
  const int nt = K >> 6;
  const long Kl = K;

  auto stA = [&](int b, int half, int tile) {
#pragma unroll
    for (int q = 0; q < 2; ++q) {
      int rl = (wave * 2 + q) * 8 + (lane >> 3);
      int c = (lane & 7) ^ (rl & 7);
      gl2lds16(A + (m0 + half * 128 + rl) * Kl + ((long)tile << 6) + c * 8,
               &lds[b][half * 8192 + (wave * 2 + q) * 512]);
    }
  };
  auto stB = [&](int b, int half, int tile) {
#pragma unroll
    for (int q = 0; q < 2; ++q) {
      int rl = (wave * 2 + q) * 8 + (lane >> 3);
      int c = (lane & 7) ^ (rl & 7);
      gl2lds16(W + (n0 + half * 128 + rl) * Kl + ((long)tile << 6) + c * 8,
               &lds[b][BM * 64 + half * 8192 + (wave * 2 + q) * 512]);
    }
  };

  f32x4 acc[IM][4] = {};
  short8 af[4][2], bf[2][2];

#define LDAF(IH)                                                              \
  _Pragma("unroll") for (int ii2 = 0; ii2 < 4; ++ii2) {                       \
    int row = (((IH)*4 + ii2) * 2 + wm) * 16 + r16;                           \
    _Pragma("unroll") for (int kk = 0; kk < 2; ++kk)                          \
        af[ii2][kk] = *(const short8*)(&lds[cur][row * 64 +                   \
                                        (((kk << 2) | g) ^ (row & 7)) * 8]);  \
  }
#define LDBF(JH)                                                              \
  _Pragma("unroll") for (int jj2 = 0; jj2 < 2; ++jj2) {                       \
    int row = (((JH)*2 + jj2) * 4 + wn) * 16 + r16;                           \
    _Pragma("unroll") for (int kk = 0; kk < 2; ++kk)                          \
        bf[jj2][kk] = *(const short8*)(&lds[cur][BM * 64 + row * 64 +         \
                                        (((kk << 2) | g) ^ (row & 7)) * 8]);  \
  }
#define MFMA_PH(IH, JH)                                                       \
  __builtin_amdgcn_s_setprio(1);                                              \
  _Pragma("unroll") for (int ii2 = 0; ii2 < 4; ++ii2)                         \
      _Pragma("unroll") for (int jj2 = 0; jj2 < 2; ++jj2)                     \
          _Pragma("unroll") for (int kk = 0; kk < 2; ++kk)                    \
              acc[(IH)*4 + ii2][(JH)*2 + jj2] =                               \
                  __builtin_amdgcn_mfma_f32_16x16x32_bf16(                    \
                      af[ii2][kk], bf[jj2][kk],                               \
                      acc[(IH)*4 + ii2][(JH)*2 + jj2], 0, 0, 0);              \
  __builtin_amdgcn_s_setprio(0);

  // prologue: stage tile 0 into buf 0 in schedule order
  if constexpr (IM == 8) {
    stA(0, 0, 0); stB(0, 0, 0); stB(0, 1, 0); stA(0, 1, 0);
    VMW4();
  } else {
    stA(0, 0, 0); stB(0, 0, 0); stB(0, 1, 0);
    VMW2();
  }
  BARRIER();

  for (int tt = 0; tt < nt; ++tt) {
    const int cur = tt & 1, nxt = cur ^ 1;
    const int ts = (tt + 1 < nt) ? tt + 1 : tt;  // clamped prefetch tile
    if constexpr (IM == 8) {
      LDAF(0); LDBF(0);
      stA(nxt, 0, ts);
      MFMA_PH(0, 0);
      VMW4(); BARRIER();
      LDBF(1);
      stB(nxt, 0, ts);
      MFMA_PH(0, 1);
      VMW4(); BARRIER();
      LDAF(1); LDBF(0);
      stB(nxt, 1, ts);
      MFMA_PH(1, 0);
      BARRIER();
      LDBF(1);
      stA(nxt, 1, ts);
      MFMA_PH(1, 1);
      VMW4(); BARRIER();
    } else {
      LDAF(0); LDBF(0);
      stA(nxt, 0, ts); stB(nxt, 0, ts);
      MFMA_PH(0, 0);
      VMW4(); BARRIER();
      LDBF(1);
      stB(nxt, 1, ts);
      MFMA_PH(0, 1);
      VMW2(); BARRIER();
    }
  }
  VMW0();

  const long Nl = N;
#pragma unroll
  for (int ii = 0; ii < IM; ++ii) {
#pragma unroll
    for (int jj = 0; jj < 4; ++jj) {
#pragma unroll
      for (int r = 0; r < 4; ++r) {
        long mg = m0 + (ii * 2 + wm) * 16 + g * 4 + r;
        long ng = n0 + (jj * 4 + wn) * 16 + r16;
        float v = acc[ii][jj][r];
        if constexpr (MODE == 0) {
          long which = ng >> 11;          // 0=q,1=k,2=v (uniform per 256-tile)
          long nloc = ng & 2047;
          long bb = mg >> 11, sq = mg & 2047;
          long hh = nloc >> 7, dd = nloc & 127;
          long idx = (which < 2) ? (((bb * 16 + hh) * 2048 + sq) * 128 + dd)
                                 : (((bb * 16 + hh) * 128 + dd) * 2048 + sq);
          ((u16*)outp)[which * 8388608 + idx] = f2bf(v);
        } else if constexpr (MODE == 2) {
          v += bias[ng] + resid[mg * Nl + ng];
          ((u16*)outp)[mg * Nl + ng] = f2bf(v);
        } else if constexpr (MODE == 3) {
          v = gelu_exact(v + bias[ng]);
          ((u16*)outp)[mg * Nl + ng] = f2bf(v);
        } else {
          v += bias[ng] + resid[mg * Nl + ng];
          ((float*)outp)[mg * Nl + ng] = v;
        }
      }
    }
  }
#undef LDAF
#undef LDBF
#undef MFMA_PH
}

// =====================================================================
// Flash attention: 32x32 MFMA, swapped QK^T, in-register softmax.
// =====================================================================
__global__ __launch_bounds__(256, 2) void attn2_k(const u16* __restrict__ Qp,
                                                  const u16* __restrict__ Kp,
                                                  const u16* __restrict__ Vp,
                                                  u16* __restrict__ ctx) {
  __shared__ __align__(16) u16 KsL[2][64 * 128];
  __shared__ __align__(16) u16 VsL[2][128 * 64];
  const int qt = gridDim.x - 1 - blockIdx.x;
  const int bh = blockIdx.y;
  const int t = threadIdx.x, lane = t & 63, wave = t >> 6;
  const int l31 = lane & 31, hi = lane >> 5;
  const int q0 = qt * 128, qw0 = q0 + wave * 32;
  const int qg = qw0 + l31;
  const u16* Qh = Qp + (long)bh * 2048 * 128;
  const u16* Kh = Kp + (long)bh * 2048 * 128;
  const u16* Vh = Vp + (long)bh * 128 * 2048;
  const int nkt = qt * 2 + 2;
  const int ktmax = (qw0 + 31) >> 6;
  const float cs = 0.12753042923810058f;  // (1/sqrt(128)) * log2(e)

  short8 qf[8];
#pragma unroll
  for (int ds = 0; ds < 8; ++ds)
    qf[ds] = *(const short8*)(Qh + (long)qg * 128 + ds * 16 + hi * 8);

  f32x16 O0 = {}, O1 = {}, O2 = {}, O3 = {};
  float m = -INFINITY, l = 0.f;

  auto stage = [&](int b, int kt) {
#pragma unroll
    for (int q = 0; q < 4; ++q) {
      int r = wave * 16 + q * 4 + (lane >> 4);
      int c = (lane & 15) ^ (r & 15);
      gl2lds16(Kh + ((long)kt * 64 + r) * 128 + c * 8,
               &KsL[b][(wave * 16 + q * 4) * 128]);
    }
#pragma unroll
    for (int q = 0; q < 4; ++q) {
      int r = wave * 32 + q * 8 + (lane >> 3);
      int c = (lane & 7) ^ (r & 7);
      gl2lds16(Vh + (long)r * 2048 + kt * 64 + c * 8,
               &VsL[b][(wave * 32 + q * 8) * 64]);
    }
  };

  stage(0, 0);
  VMW0(); BARRIER();

  for (int kt = 0; kt < nkt; ++kt) {
    const int cur = kt & 1;
    if (kt + 1 < nkt) stage(cur ^ 1, kt + 1);
    if (kt <= ktmax) {
      f32x16 S0 = {}, S1 = {};
      __builtin_amdgcn_s_setprio(1);
#pragma unroll
      for (int ds = 0; ds < 8; ++ds) {
        int c0 = ((ds * 2 + hi) ^ (l31 & 15)) * 8;
        short8 k0 = *(const short8*)(&KsL[cur][l31 * 128 + c0]);
        int r1 = 32 + l31;
        int c1 = ((ds * 2 + hi) ^ (r1 & 15)) * 8;
        short8 k1 = *(const short8*)(&KsL[cur][r1 * 128 + c1]);
        S0 = __builtin_amdgcn_mfma_f32_32x32x16_bf16(k0, qf[ds], S0, 0, 0, 0);
        S1 = __builtin_amdgcn_mfma_f32_32x32x16_bf16(k1, qf[ds], S1, 0, 0, 0);
      }
      __builtin_amdgcn_s_setprio(0);
      float p[32];
#pragma unroll
      for (int i = 0; i < 16; ++i) { p[i] = S0[i]; p[16 + i] = S1[i]; }
      if (kt * 64 + 63 > qw0) {
#pragma unroll
        for (int ks = 0; ks < 2; ++ks)
#pragma unroll
          for (int r = 0; r < 16; ++r) {
            int kg = kt * 64 + ks * 32 + (r & 3) + 8 * (r >> 2) + 4 * hi;
            if (kg > qg) p[ks * 16 + r] = -INFINITY;
          }
      }
      float tmax = p[0];
#pragma unroll
      for (int i = 1; i < 32; ++i) tmax = fmaxf(tmax, p[i]);
      tmax = fmaxf(tmax, __shfl_xor(tmax, 32));
      float mnew = fmaxf(m, tmax);
      float corr = __builtin_amdgcn_exp2f((m - mnew) * cs);
      float ls = 0.f;
#pragma unroll
      for (int i = 0; i < 32; ++i) {
        p[i] = __builtin_amdgcn_exp2f((p[i] - mnew) * cs);
        ls += p[i];
      }
      ls += __shfl_xor(ls, 32);
      l = l * corr + ls;
      m = mnew;
#pragma unroll
      for (int i = 0; i < 16; ++i) {
        O0[i] *= corr; O1[i] *= corr; O2[i] *= corr; O3[i] *= corr;
      }
      short8 pf[4];
#pragma unroll
      for (int gg = 0; gg < 4; ++gg) {
        u32 u_, v_, w_, z_;
        asm("v_cvt_pk_bf16_f32 %0, %1, %2" : "=v"(u_) : "v"(p[gg * 8 + 0]), "v"(p[gg * 8 + 1]));
        asm("v_cvt_pk_bf16_f32 %0, %1, %2" : "=v"(v_) : "v"(p[gg * 8 + 2]), "v"(p[gg * 8 + 3]));
        asm("v_cvt_pk_bf16_f32 %0, %1, %2" : "=v"(w_) : "v"(p[gg * 8 + 4]), "v"(p[gg * 8 + 5]));
        asm("v_cvt_pk_bf16_f32 %0, %1, %2" : "=v"(z_) : "v"(p[gg * 8 + 6]), "v"(p[gg * 8 + 7]));
        asm("v_permlane32_swap_b32 %0, %1" : "+v"(u_), "+v"(w_));
        asm("v_permlane32_swap_b32 %0, %1" : "+v"(v_), "+v"(z_));
        union { u32 w4[4]; short8 s; } cv;
        cv.w4[0] = u_; cv.w4[1] = v_; cv.w4[2] = w_; cv.w4[3] = z_;
        pf[gg] = cv.s;
      }
      __builtin_amdgcn_s_setprio(1);
#define PVROW(ds, OO)                                                          \
  {                                                                            \
    int row = (ds)*32 + l31;                                                   \
    _Pragma("unroll") for (int gg = 0; gg < 4; ++gg) {                         \
      short8 vf = *(const short8*)(&VsL[cur][row * 64 +                        \
                                             (((gg * 2 + hi) ^ (row & 7)) * 8)]); \
      OO = __builtin_amdgcn_mfma_f32_32x32x16_bf16(vf, pf[gg], OO, 0, 0, 0);   \
    }                                                                          \
  }
      PVROW(0, O0); PVROW(1, O1); PVROW(2, O2); PVROW(3, O3);
#undef PVROW
      __builtin_amdgcn_s_setprio(0);
    }
    VMW0(); BARRIER();
  }

  const float inv = 1.f / l;
  u16* cp = ctx + ((long)(bh >> 4) * 2048 + qg) * 2048 + (bh & 15) * 128;
#define WROUT(OO, dsb)                                                         \
  _Pragma("unroll") for (int rg = 0; rg < 4; ++rg) {                           \
    int d = (dsb)*32 + 8 * rg + 4 * hi;                                        \
    u32x2 wv;                                                                  \
    wv[0] = packbf2(OO[4 * rg] * inv, OO[4 * rg + 1] * inv);                   \
    wv[1] = packbf2(OO[4 * rg + 2] * inv, OO[4 * rg + 3] * inv);               \
    *(u32x2*)(cp + d) = wv;                                                    \
  }
  WROUT(O0, 0); WROUT(O1, 1); WROUT(O2, 2); WROUT(O3, 3);
#undef WROUT
}

extern "C" void kernel_launch(void* const* d_in, const int* in_sizes, int n_in,
                              void* d_out, int out_size, void* d_ws, size_t ws_size,
                              hipStream_t stream) {
  const float* x = (const float*)d_in[0];
  const float* ln1w = (const float*)d_in[1];
  const float* ln1b = (const float*)d_in[2];
  const float* wq = (const float*)d_in[3];
  const float* wk = (const float*)d_in[4];
  const float* wv = (const float*)d_in[5];
  const float* wo = (const float*)d_in[6];
  const float* bo = (const float*)d_in[7];
  const float* ln2w = (const float*)d_in[8];
  const float* ln2b = (const float*)d_in[9];
  const float* w1 = (const float*)d_in[10];
  const float* b1 = (const float*)d_in[11];
  const float* w2 = (const float*)d_in[12];
  const float* b2 = (const float*)d_in[13];
  float* out = (float*)d_out;
  char* ws = (char*)d_ws;

  float* x1f = (float*)(ws + 0);            // 33,554,432 B (x1 fp32, w2 resid)
  u16* x1b = (u16*)(ws + 33554432);         // 16,777,216
  u16* wqt = (u16*)(ws + 50331648);         //  8,388,608 (wq/wk/wv contiguous = [6144,2048])
  u16* wkt = (u16*)(ws + 58720256);
  u16* wvt = (u16*)(ws + 67108864);
  u16* wot = (u16*)(ws + 75497472);
  u16* w1t = (u16*)(ws + 83886080);         // 33,554,432
  u16* w2t = (u16*)(ws + 117440512);        // 33,554,432
  u16* qb = (u16*)(ws + 150994944);         // 16,777,216 (q/k/v contiguous)
  u16* kb = (u16*)(ws + 167772160);
  u16* vb = (u16*)(ws + 184549376);
  u16* ctxb = (u16*)(ws + 201326592);
  u16* ab = (u16*)(ws + 218103808);
  u16* y0b = (u16*)(ws + 234881024);        // ends 251,658,240
  u16* hb = qb;                              // 64 MB alias over q/k/v/ctx

  tconvln_k<<<53248, 256, 0, stream>>>(wq, wk, wv, wo, w1, w2,
                                       wqt, wkt, wvt, wot, w1t, w2t,
                                       x, ln1w, ln1b, x1f, x1b);
  gemm8_k<0, 4><<<dim3(32, 24), 512, 0, stream>>>(x1b, wqt, qb, nullptr, nullptr, 4096, 6144, 2048);
  attn2_k<<<dim3(16, 32), 256, 0, stream>>>(qb, kb, vb, ctxb);
  gemm8_k<2, 4><<<dim3(32, 8), 512, 0, stream>>>(ctxb, wot, ab, bo, x, 4096, 2048, 2048);
  ln2_k<<<4096, 256, 0, stream>>>(ab, ln2w, ln2b, y0b);
  gemm8_k<3, 8><<<dim3(16, 32), 512, 0, stream>>>(y0b, w1t, hb, b1, nullptr, 4096, 8192, 2048);
  gemm8_k<4, 4><<<dim3(32, 8), 512, 0, stream>>>(hb, w2t, out, b2, x1f, 4096, 2048, 8192);
}

// Round 14
// 634.304 us; speedup vs baseline: 1.0452x; 1.0452x over previous
//
#include <hip/hip_runtime.h>
#include <math.h>

typedef unsigned short u16;
typedef unsigned int u32;
typedef __attribute__((ext_vector_type(8))) short short8;
typedef __attribute__((ext_vector_type(4))) float f32x4;
typedef __attribute__((ext_vector_type(16))) float f32x16;
typedef __attribute__((ext_vector_type(4))) u32 u32x4;
typedef __attribute__((ext_vector_type(2))) u32 u32x2;

#define DEVFN static __device__ __forceinline__

DEVFN u16 f2bf(float x) {
  union { float f; u32 u; } v; v.f = x;
  u32 r = v.u + 0x7fffu + ((v.u >> 16) & 1u);
  return (u16)(r >> 16);
}
DEVFN float bf2f(u16 h) {
  union { u32 u; float f; } v; v.u = ((u32)h) << 16;
  return v.f;
}
DEVFN u32 packbf2(float a, float b) {
  return (u32)f2bf(a) | ((u32)f2bf(b) << 16);
}
DEVFN void gl2lds16(const u16* g, u16* l) {
  __builtin_amdgcn_global_load_lds(
      (const __attribute__((address_space(1))) u32*)g,
      (__attribute__((address_space(3))) u32*)l, 16, 0, 0);
}
// exact GELU via A&S 7.1.26 erf approx (|eps|<=1.5e-7)
DEVFN float gelu_exact(float v) {
  float s = v * 0.70710678118654752f;
  float ax = fabsf(s);
  float t = __builtin_amdgcn_rcpf(1.0f + 0.3275911f * ax);
  float poly = t * (0.254829592f +
               t * (-0.284496736f +
               t * (1.421413741f +
               t * (-1.453152027f + t * 1.061405429f))));
  float e = __expf(-s * s);
  float er = 1.0f - poly * e;
  er = (s < 0.f) ? -er : er;
  return 0.5f * v * (1.0f + er);
}

#define VMW4() asm volatile("s_waitcnt vmcnt(4)" ::: "memory")
#define VMW2() asm volatile("s_waitcnt vmcnt(2)" ::: "memory")
#define VMW0() asm volatile("s_waitcnt vmcnt(0)" ::: "memory")
#define CFENCE() asm volatile("" ::: "memory")
#define BARRIER() do { CFENCE(); __builtin_amdgcn_s_barrier(); CFENCE(); } while (0)

// ---------------- fused: transpose+convert all 6 weights  AND  ln1.
// blocks [0,16384): wq/wk/wv/wo  [16384,32768): w1  [32768,49152): w2
// blocks [49152,53248): ln1 rows (one block per row of x)
__global__ __launch_bounds__(256) void tconvln_k(
    const float* __restrict__ wq, const float* __restrict__ wk,
    const float* __restrict__ wv, const float* __restrict__ wo,
    const float* __restrict__ w1, const float* __restrict__ w2,
    u16* __restrict__ wqt, u16* __restrict__ wkt, u16* __restrict__ wvt,
    u16* __restrict__ wot, u16* __restrict__ w1t, u16* __restrict__ w2t,
    const float* __restrict__ x, const float* __restrict__ ln1w,
    const float* __restrict__ ln1b, float* __restrict__ y32,
    u16* __restrict__ y16) {
  int b = blockIdx.x;
  int t = threadIdx.x;
  if (b >= 49152) {  // ---- ln1 row
    long base = (long)(b - 49152) * 2048;
    float4 v0 = ((const float4*)(x + base))[2 * t];
    float4 v1 = ((const float4*)(x + base))[2 * t + 1];
    float xv[8];
    *(float4*)xv = v0; *(float4*)(xv + 4) = v1;
    float s = 0.f, ss = 0.f;
#pragma unroll
    for (int i = 0; i < 8; ++i) { s += xv[i]; ss += xv[i] * xv[i]; }
#pragma unroll
    for (int m = 1; m < 64; m <<= 1) { s += __shfl_xor(s, m); ss += __shfl_xor(ss, m); }
    __shared__ float rs[4], rss[4];
    int wave = t >> 6;
    if ((t & 63) == 0) { rs[wave] = s; rss[wave] = ss; }
    __syncthreads();
    s = rs[0] + rs[1] + rs[2] + rs[3];
    ss = rss[0] + rss[1] + rss[2] + rss[3];
    float mean = s * (1.f / 2048.f);
    float var = ss * (1.f / 2048.f) - mean * mean;
    float inv = rsqrtf(var + 1e-5f);
    float wv8[8], bv[8];
    *(float4*)wv8 = ((const float4*)ln1w)[2 * t];
    *(float4*)(wv8 + 4) = ((const float4*)ln1w)[2 * t + 1];
    *(float4*)bv = ((const float4*)ln1b)[2 * t];
    *(float4*)(bv + 4) = ((const float4*)ln1b)[2 * t + 1];
    float yv[8];
#pragma unroll
    for (int i = 0; i < 8; ++i) yv[i] = (xv[i] - mean) * inv * wv8[i] + bv[i];
    ((float4*)(y32 + base))[2 * t] = *(float4*)yv;
    ((float4*)(y32 + base))[2 * t + 1] = *(float4*)(yv + 4);
    u32x4 ov;
#pragma unroll
    for (int i = 0; i < 4; ++i) ov[i] = packbf2(yv[2 * i], yv[2 * i + 1]);
    ((u32x4*)(y16 + base))[t] = ov;
    return;
  }
  // ---- weight transpose tile
  __shared__ float tile[32][33];
  const float* in; u16* out; int K, N, tn, tk;
  if (b < 16384) {
    int wsel = b >> 12;
    int loc = b & 4095;
    in = (wsel == 0) ? wq : (wsel == 1) ? wk : (wsel == 2) ? wv : wo;
    out = (wsel == 0) ? wqt : (wsel == 1) ? wkt : (wsel == 2) ? wvt : wot;
    K = 2048; N = 2048; tn = loc & 63; tk = loc >> 6;
  } else if (b < 32768) {
    int loc = b - 16384; in = w1; out = w1t; K = 2048; N = 8192;
    tn = loc & 255; tk = loc >> 8;
  } else {
    int loc = b - 32768; in = w2; out = w2t; K = 8192; N = 2048;
    tn = loc & 63; tk = loc >> 6;
  }
  int n0 = tn << 5, k0 = tk << 5;
  int tx = t & 31, ty = t >> 5;
#pragma unroll
  for (int i = 0; i < 32; i += 8)
    tile[ty + i][tx] = in[(long)(k0 + ty + i) * N + n0 + tx];
  __syncthreads();
#pragma unroll
  for (int i = 0; i < 32; i += 8)
    out[(long)(n0 + ty + i) * K + k0 + tx] = f2bf(tile[tx][ty + i]);
}

// ---------------- LayerNorm (bf16 in) -> bf16 out.
__global__ __launch_bounds__(256) void ln2_k(const u16* __restrict__ a,
                                             const float* __restrict__ w,
                                             const float* __restrict__ b,
                                             u16* __restrict__ y) {
  long base = (long)blockIdx.x * 2048;
  int t = threadIdx.x;
  u32x4 pv = ((const u32x4*)(a + base))[t];
  float xv[8];
#pragma unroll
  for (int i = 0; i < 4; ++i) {
    xv[2 * i] = bf2f((u16)(pv[i] & 0xffffu));
    xv[2 * i + 1] = bf2f((u16)(pv[i] >> 16));
  }
  float s = 0.f, ss = 0.f;
#pragma unroll
  for (int i = 0; i < 8; ++i) { s += xv[i]; ss += xv[i] * xv[i]; }
#pragma unroll
  for (int m = 1; m < 64; m <<= 1) { s += __shfl_xor(s, m); ss += __shfl_xor(ss, m); }
  __shared__ float rs[4], rss[4];
  int wave = t >> 6;
  if ((t & 63) == 0) { rs[wave] = s; rss[wave] = ss; }
  __syncthreads();
  s = rs[0] + rs[1] + rs[2] + rs[3];
  ss = rss[0] + rss[1] + rss[2] + rss[3];
  float mean = s * (1.f / 2048.f);
  float var = ss * (1.f / 2048.f) - mean * mean;
  float inv = rsqrtf(var + 1e-5f);
  float wv[8], bv[8];
  *(float4*)wv = ((const float4*)w)[2 * t]; *(float4*)(wv + 4) = ((const float4*)w)[2 * t + 1];
  *(float4*)bv = ((const float4*)b)[2 * t]; *(float4*)(bv + 4) = ((const float4*)b)[2 * t + 1];
  u32x4 ov;
#pragma unroll
  for (int i = 0; i < 4; ++i) {
    float y0 = (xv[2 * i] - mean) * inv * wv[2 * i] + bv[2 * i];
    float y1 = (xv[2 * i + 1] - mean) * inv * wv[2 * i + 1] + bv[2 * i + 1];
    ov[i] = packbf2(y0, y1);
  }
  ((u32x4*)(y + base))[t] = ov;
}

// =====================================================================
// Phase-scheduled GEMM (r3 engine — measured best: 0 conflicts, ~165 us
// per big GEMM). 512 threads = 8 waves (2M x 4N). BK=64. BN=256.
// IM=8 -> BM=256 (4 phases), IM=4 -> BM=128 (2 phases).
// MODE 0: fused QKV (W=[6144,2048]) -> q/k [B,H,S,D], v [B,H,D,S]
// MODE 2: +bias+resid(f32) -> bf16   MODE 3: +bias, exact GELU -> bf16
// MODE 4: +bias+resid(f32) -> f32
// MODE 5: w2 split-K/2 (W=[2048,8192], call K=4096) -> f32 partials
// =====================================================================
template <int MODE, int IM>
__global__ __launch_bounds__(512, 2) void gemm8_k(const u16* __restrict__ A,
                                                  const u16* __restrict__ W,
                                                  void* __restrict__ outp,
                                                  const float* __restrict__ bias,
                                                  const float* __restrict__ resid,
                                                  int M, int N, int K) {
  constexpr int BM = IM * 32;  // 256 or 128
  constexpr int BN = 256;
  __shared__ __align__(16) u16 lds[2][(BM + BN) * 64];
  const int t = threadIdx.x, lane = t & 63, wave = t >> 6;
  const int g = lane >> 4, r16 = lane & 15;
  const int wm = wave >> 2, wn = wave & 3;
  const int nM = M / BM;
  const int nwg = gridDim.x * gridDim.y;
  const int orig = blockIdx.y * gridDim.x + blockIdx.x;
  const int sw = (nwg & 7) ? orig : ((orig & 7) * (nwg >> 3) + (orig >> 3));
  const long m0 = (long)(sw % nM) * BM;
  long n0, k0;
  int ks = 0;
  if constexpr (MODE == 5) {
    int rest = sw / nM;            // 0..15
    n0 = (long)(rest & 7) * BN;
    ks = rest >> 3;
    k0 = (long)ks * 4096;
  } else {
    n0 = (long)(sw / nM) * BN;
    k0 = 0;
  }
  const int nt = K >> 6;
  const long Kl = (MODE == 5) ? 8192 : K;

  auto stA = [&](int b, int half, int tile) {
#pragma unroll
    for (int q = 0; q < 2; ++q) {
      int rl = (wave * 2 + q) * 8 + (lane >> 3);
      int c = (lane & 7) ^ (rl & 7);
      gl2lds16(A + (m0 + half * 128 + rl) * Kl + k0 + ((long)tile << 6) + c * 8,
               &lds[b][half * 8192 + (wave * 2 + q) * 512]);
    }
  };
  auto stB = [&](int b, int half, int tile) {
#pragma unroll
    for (int q = 0; q < 2; ++q) {
      int rl = (wave * 2 + q) * 8 + (lane >> 3);
      int c = (lane & 7) ^ (rl & 7);
      gl2lds16(W + (n0 + half * 128 + rl) * Kl + k0 + ((long)tile << 6) + c * 8,
               &lds[b][BM * 64 + half * 8192 + (wave * 2 + q) * 512]);
    }
  };

  f32x4 acc[IM][4] = {};
  short8 af[4][2], bf[2][2];

#define LDAF(IH)                                                              \
  _Pragma("unroll") for (int ii2 = 0; ii2 < 4; ++ii2) {                       \
    int row = (((IH)*4 + ii2) * 2 + wm) * 16 + r16;                           \
    _Pragma("unroll") for (int kk = 0; kk < 2; ++kk)                          \
        af[ii2][kk] = *(const short8*)(&lds[cur][row * 64 +                   \
                                        (((kk << 2) | g) ^ (row & 7)) * 8]);  \
  }
#define LDBF(JH)                                                              \
  _Pragma("unroll") for (int jj2 = 0; jj2 < 2; ++jj2) {                       \
    int row = (((JH)*2 + jj2) * 4 + wn) * 16 + r16;                           \
    _Pragma("unroll") for (int kk = 0; kk < 2; ++kk)                          \
        bf[jj2][kk] = *(const short8*)(&lds[cur][BM * 64 + row * 64 +         \
                                        (((kk << 2) | g) ^ (row & 7)) * 8]);  \
  }
#define MFMA_PH(IH, JH)                                                       \
  __builtin_amdgcn_s_setprio(1);                                              \
  _Pragma("unroll") for (int ii2 = 0; ii2 < 4; ++ii2)                         \
      _Pragma("unroll") for (int jj2 = 0; jj2 < 2; ++jj2)                     \
          _Pragma("unroll") for (int kk = 0; kk < 2; ++kk)                    \
              acc[(IH)*4 + ii2][(JH)*2 + jj2] =                               \
                  __builtin_amdgcn_mfma_f32_16x16x32_bf16(                    \
                      af[ii2][kk], bf[jj2][kk],                               \
                      acc[(IH)*4 + ii2][(JH)*2 + jj2], 0, 0, 0);              \
  __builtin_amdgcn_s_setprio(0);

  // prologue: stage tile 0 into buf 0 in schedule order
  if constexpr (IM == 8) {
    stA(0, 0, 0); stB(0, 0, 0); stB(0, 1, 0); stA(0, 1, 0);
    VMW4();
  } else {
    stA(0, 0, 0); stB(0, 0, 0); stB(0, 1, 0);
    VMW2();
  }
  BARRIER();

  for (int tt = 0; tt < nt; ++tt) {
    const int cur = tt & 1, nxt = cur ^ 1;
    const int ts = (tt + 1 < nt) ? tt + 1 : tt;  // clamped prefetch tile
    if constexpr (IM == 8) {
      LDAF(0); LDBF(0);
      stA(nxt, 0, ts);
      MFMA_PH(0, 0);
      VMW4(); BARRIER();
      LDBF(1);
      stB(nxt, 0, ts);
      MFMA_PH(0, 1);
      VMW4(); BARRIER();
      LDAF(1); LDBF(0);
      stB(nxt, 1, ts);
      MFMA_PH(1, 0);
      BARRIER();
      LDBF(1);
      stA(nxt, 1, ts);
      MFMA_PH(1, 1);
      VMW4(); BARRIER();
    } else {
      LDAF(0); LDBF(0);
      stA(nxt, 0, ts); stB(nxt, 0, ts);
      MFMA_PH(0, 0);
      VMW4(); BARRIER();
      LDBF(1);
      stB(nxt, 1, ts);
      MFMA_PH(0, 1);
      VMW2(); BARRIER();
    }
  }
  VMW0();

  const long Nl = N;
#pragma unroll
  for (int ii = 0; ii < IM; ++ii) {
#pragma unroll
    for (int jj = 0; jj < 4; ++jj) {
#pragma unroll
      for (int r = 0; r < 4; ++r) {
        long mg = m0 + (ii * 2 + wm) * 16 + g * 4 + r;
        long ng = n0 + (jj * 4 + wn) * 16 + r16;
        float v = acc[ii][jj][r];
        if constexpr (MODE == 0) {
          long which = ng >> 11;          // 0=q,1=k,2=v (uniform per 256-tile)
          long nloc = ng & 2047;
          long bb = mg >> 11, sq = mg & 2047;
          long hh = nloc >> 7, dd = nloc & 127;
          long idx = (which < 2) ? (((bb * 16 + hh) * 2048 + sq) * 128 + dd)
                                 : (((bb * 16 + hh) * 128 + dd) * 2048 + sq);
          ((u16*)outp)[which * 8388608 + idx] = f2bf(v);
        } else if constexpr (MODE == 2) {
          v += bias[ng] + resid[mg * Nl + ng];
          ((u16*)outp)[mg * Nl + ng] = f2bf(v);
        } else if constexpr (MODE == 3) {
          v = gelu_exact(v + bias[ng]);
          ((u16*)outp)[mg * Nl + ng] = f2bf(v);
        } else if constexpr (MODE == 5) {
          ((float*)outp)[(long)ks * 8388608 + mg * 2048 + ng] = v;
        } else {
          v += bias[ng] + resid[mg * Nl + ng];
          ((float*)outp)[mg * Nl + ng] = v;
        }
      }
    }
  }
#undef LDAF
#undef LDBF
#undef MFMA_PH
}

// ---------------- split-K reducer: out = p0 + p1 + bias + resid (all f32)
__global__ __launch_bounds__(256) void red_k(const float* __restrict__ p,
                                             const float* __restrict__ bias,
                                             const float* __restrict__ resid,
                                             float* __restrict__ out) {
  long i = (long)blockIdx.x * 256 + threadIdx.x;
  for (long idx = i; idx < 2097152; idx += 2048 * 256) {
    float4 a = ((const float4*)p)[idx];
    float4 b = ((const float4*)(p + 8388608))[idx];
    float4 r = ((const float4*)resid)[idx];
    float4 bs = ((const float4*)bias)[idx & 511];
    float4 o;
    o.x = a.x + b.x + r.x + bs.x;
    o.y = a.y + b.y + r.y + bs.y;
    o.z = a.z + b.z + r.z + bs.z;
    o.w = a.w + b.w + r.w + bs.w;
    ((float4*)out)[idx] = o;
  }
}

// =====================================================================
// Flash attention: 32x32 MFMA, swapped QK^T, in-register softmax.
// =====================================================================
__global__ __launch_bounds__(256, 2) void attn2_k(const u16* __restrict__ Qp,
                                                  const u16* __restrict__ Kp,
                                                  const u16* __restrict__ Vp,
                                                  u16* __restrict__ ctx) {
  __shared__ __align__(16) u16 KsL[2][64 * 128];
  __shared__ __align__(16) u16 VsL[2][128 * 64];
  const int qt = gridDim.x - 1 - blockIdx.x;
  const int bh = blockIdx.y;
  const int t = threadIdx.x, lane = t & 63, wave = t >> 6;
  const int l31 = lane & 31, hi = lane >> 5;
  const int q0 = qt * 128, qw0 = q0 + wave * 32;
  const int qg = qw0 + l31;
  const u16* Qh = Qp + (long)bh * 2048 * 128;
  const u16* Kh = Kp + (long)bh * 2048 * 128;
  const u16* Vh = Vp + (long)bh * 128 * 2048;
  const int nkt = qt * 2 + 2;
  const int ktmax = (qw0 + 31) >> 6;
  const float cs = 0.12753042923810058f;  // (1/sqrt(128)) * log2(e)

  short8 qf[8];
#pragma unroll
  for (int ds = 0; ds < 8; ++ds)
    qf[ds] = *(const short8*)(Qh + (long)qg * 128 + ds * 16 + hi * 8);

  f32x16 O0 = {}, O1 = {}, O2 = {}, O3 = {};
  float m = -INFINITY, l = 0.f;

  auto stage = [&](int b, int kt) {
#pragma unroll
    for (int q = 0; q < 4; ++q) {
      int r = wave * 16 + q * 4 + (lane >> 4);
      int c = (lane & 15) ^ (r & 15);
      gl2lds16(Kh + ((long)kt * 64 + r) * 128 + c * 8,
               &KsL[b][(wave * 16 + q * 4) * 128]);
    }
#pragma unroll
    for (int q = 0; q < 4; ++q) {
      int r = wave * 32 + q * 8 + (lane >> 3);
      int c = (lane & 7) ^ (r & 7);
      gl2lds16(Vh + (long)r * 2048 + kt * 64 + c * 8,
               &VsL[b][(wave * 32 + q * 8) * 64]);
    }
  };

  stage(0, 0);
  VMW0(); BARRIER();

  for (int kt = 0; kt < nkt; ++kt) {
    const int cur = kt & 1;
    if (kt + 1 < nkt) stage(cur ^ 1, kt + 1);
    if (kt <= ktmax) {
      f32x16 S0 = {}, S1 = {};
      __builtin_amdgcn_s_setprio(1);
#pragma unroll
      for (int ds = 0; ds < 8; ++ds) {
        int c0 = ((ds * 2 + hi) ^ (l31 & 15)) * 8;
        short8 k0 = *(const short8*)(&KsL[cur][l31 * 128 + c0]);
        int r1 = 32 + l31;
        int c1 = ((ds * 2 + hi) ^ (r1 & 15)) * 8;
        short8 k1 = *(const short8*)(&KsL[cur][r1 * 128 + c1]);
        S0 = __builtin_amdgcn_mfma_f32_32x32x16_bf16(k0, qf[ds], S0, 0, 0, 0);
        S1 = __builtin_amdgcn_mfma_f32_32x32x16_bf16(k1, qf[ds], S1, 0, 0, 0);
      }
      __builtin_amdgcn_s_setprio(0);
      float p[32];
#pragma unroll
      for (int i = 0; i < 16; ++i) { p[i] = S0[i]; p[16 + i] = S1[i]; }
      if (kt * 64 + 63 > qw0) {
#pragma unroll
        for (int ks = 0; ks < 2; ++ks)
#pragma unroll
          for (int r = 0; r < 16; ++r) {
            int kg = kt * 64 + ks * 32 + (r & 3) + 8 * (r >> 2) + 4 * hi;
            if (kg > qg) p[ks * 16 + r] = -INFINITY;
          }
      }
      float tmax = p[0];
#pragma unroll
      for (int i = 1; i < 32; ++i) tmax = fmaxf(tmax, p[i]);
      tmax = fmaxf(tmax, __shfl_xor(tmax, 32));
      float mnew = fmaxf(m, tmax);
      float corr = __builtin_amdgcn_exp2f((m - mnew) * cs);
      float ls = 0.f;
#pragma unroll
      for (int i = 0; i < 32; ++i) {
        p[i] = __builtin_amdgcn_exp2f((p[i] - mnew) * cs);
        ls += p[i];
      }
      ls += __shfl_xor(ls, 32);
      l = l * corr + ls;
      m = mnew;
#pragma unroll
      for (int i = 0; i < 16; ++i) {
        O0[i] *= corr; O1[i] *= corr; O2[i] *= corr; O3[i] *= corr;
      }
      short8 pf[4];
#pragma unroll
      for (int gg = 0; gg < 4; ++gg) {
        u32 u_, v_, w_, z_;
        asm("v_cvt_pk_bf16_f32 %0, %1, %2" : "=v"(u_) : "v"(p[gg * 8 + 0]), "v"(p[gg * 8 + 1]));
        asm("v_cvt_pk_bf16_f32 %0, %1, %2" : "=v"(v_) : "v"(p[gg * 8 + 2]), "v"(p[gg * 8 + 3]));
        asm("v_cvt_pk_bf16_f32 %0, %1, %2" : "=v"(w_) : "v"(p[gg * 8 + 4]), "v"(p[gg * 8 + 5]));
        asm("v_cvt_pk_bf16_f32 %0, %1, %2" : "=v"(z_) : "v"(p[gg * 8 + 6]), "v"(p[gg * 8 + 7]));
        asm("v_permlane32_swap_b32 %0, %1" : "+v"(u_), "+v"(w_));
        asm("v_permlane32_swap_b32 %0, %1" : "+v"(v_), "+v"(z_));
        union { u32 w4[4]; short8 s; } cv;
        cv.w4[0] = u_; cv.w4[1] = v_; cv.w4[2] = w_; cv.w4[3] = z_;
        pf[gg] = cv.s;
      }
      __builtin_amdgcn_s_setprio(1);
#define PVROW(ds, OO)                                                          \
  {                                                                            \
    int row = (ds)*32 + l31;                                                   \
    _Pragma("unroll") for (int gg = 0; gg < 4; ++gg) {                         \
      short8 vf = *(const short8*)(&VsL[cur][row * 64 +                        \
                                             (((gg * 2 + hi) ^ (row & 7)) * 8)]); \
      OO = __builtin_amdgcn_mfma_f32_32x32x16_bf16(vf, pf[gg], OO, 0, 0, 0);   \
    }                                                                          \
  }
      PVROW(0, O0); PVROW(1, O1); PVROW(2, O2); PVROW(3, O3);
#undef PVROW
      __builtin_amdgcn_s_setprio(0);
    }
    VMW0(); BARRIER();
  }

  const float inv = 1.f / l;
  u16* cp = ctx + ((long)(bh >> 4) * 2048 + qg) * 2048 + (bh & 15) * 128;
#define WROUT(OO, dsb)                                                         \
  _Pragma("unroll") for (int rg = 0; rg < 4; ++rg) {                           \
    int d = (dsb)*32 + 8 * rg + 4 * hi;                                        \
    u32x2 wv;                                                                  \
    wv[0] = packbf2(OO[4 * rg] * inv, OO[4 * rg + 1] * inv);                   \
    wv[1] = packbf2(OO[4 * rg + 2] * inv, OO[4 * rg + 3] * inv);               \
    *(u32x2*)(cp + d) = wv;                                                    \
  }
  WROUT(O0, 0); WROUT(O1, 1); WROUT(O2, 2); WROUT(O3, 3);
#undef WROUT
}

extern "C" void kernel_launch(void* const* d_in, const int* in_sizes, int n_in,
                              void* d_out, int out_size, void* d_ws, size_t ws_size,
                              hipStream_t stream) {
  const float* x = (const float*)d_in[0];
  const float* ln1w = (const float*)d_in[1];
  const float* ln1b = (const float*)d_in[2];
  const float* wq = (const float*)d_in[3];
  const float* wk = (const float*)d_in[4];
  const float* wv = (const float*)d_in[5];
  const float* wo = (const float*)d_in[6];
  const float* bo = (const float*)d_in[7];
  const float* ln2w = (const float*)d_in[8];
  const float* ln2b = (const float*)d_in[9];
  const float* w1 = (const float*)d_in[10];
  const float* b1 = (const float*)d_in[11];
  const float* w2 = (const float*)d_in[12];
  const float* b2 = (const float*)d_in[13];
  float* out = (float*)d_out;
  char* ws = (char*)d_ws;

  float* x1f = (float*)(ws + 0);            // 33,554,432 B (x1 fp32, w2 resid)
  u16* x1b = (u16*)(ws + 33554432);         // 16,777,216
  u16* wqt = (u16*)(ws + 50331648);         //  8,388,608 (wq/wk/wv contiguous = [6144,2048])
  u16* wkt = (u16*)(ws + 58720256);
  u16* wvt = (u16*)(ws + 67108864);
  u16* wot = (u16*)(ws + 75497472);
  u16* w1t = (u16*)(ws + 83886080);         // 33,554,432
  u16* w2t = (u16*)(ws + 117440512);        // 33,554,432
  u16* qb = (u16*)(ws + 150994944);         // 16,777,216 (q/k/v contiguous)
  u16* kb = (u16*)(ws + 167772160);
  u16* vb = (u16*)(ws + 184549376);
  u16* ctxb = (u16*)(ws + 201326592);
  u16* ab = (u16*)(ws + 218103808);
  u16* y0b = (u16*)(ws + 234881024);        // ends 251,658,240
  u16* hb = qb;                              // 64 MB alias over q/k/v/ctx
  float* pbuf = (float*)(ws + 50331648);     // 64 MB split-K partials
                                             // (wqt..w1t dead by w2 time)

  tconvln_k<<<53248, 256, 0, stream>>>(wq, wk, wv, wo, w1, w2,
                                       wqt, wkt, wvt, wot, w1t, w2t,
                                       x, ln1w, ln1b, x1f, x1b);
  gemm8_k<0, 8><<<dim3(16, 24), 512, 0, stream>>>(x1b, wqt, qb, nullptr, nullptr, 4096, 6144, 2048);
  attn2_k<<<dim3(16, 32), 256, 0, stream>>>(qb, kb, vb, ctxb);
  gemm8_k<2, 4><<<dim3(32, 8), 512, 0, stream>>>(ctxb, wot, ab, bo, x, 4096, 2048, 2048);
  ln2_k<<<4096, 256, 0, stream>>>(ab, ln2w, ln2b, y0b);
  gemm8_k<3, 8><<<dim3(16, 32), 512, 0, stream>>>(y0b, w1t, hb, b1, nullptr, 4096, 8192, 2048);
  gemm8_k<5, 8><<<dim3(16, 16), 512, 0, stream>>>(hb, w2t, pbuf, nullptr, nullptr, 4096, 2048, 4096);
  red_k<<<2048, 256, 0, stream>>>(pbuf, b2, x1f, out);
}

// Round 15
// 623.656 us; speedup vs baseline: 1.0631x; 1.0171x over previous
//
#include <hip/hip_runtime.h>
#include <math.h>

typedef unsigned short u16;
typedef unsigned int u32;
typedef __attribute__((ext_vector_type(8))) short short8;
typedef __attribute__((ext_vector_type(4))) float f32x4;
typedef __attribute__((ext_vector_type(16))) float f32x16;
typedef __attribute__((ext_vector_type(4))) u32 u32x4;
typedef __attribute__((ext_vector_type(2))) u32 u32x2;

#define DEVFN static __device__ __forceinline__

DEVFN u16 f2bf(float x) {
  union { float f; u32 u; } v; v.f = x;
  u32 r = v.u + 0x7fffu + ((v.u >> 16) & 1u);
  return (u16)(r >> 16);
}
DEVFN float bf2f(u16 h) {
  union { u32 u; float f; } v; v.u = ((u32)h) << 16;
  return v.f;
}
DEVFN u32 packbf2(float a, float b) {
  return (u32)f2bf(a) | ((u32)f2bf(b) << 16);
}
DEVFN void gl2lds16(const u16* g, u16* l) {
  __builtin_amdgcn_global_load_lds(
      (const __attribute__((address_space(1))) u32*)g,
      (__attribute__((address_space(3))) u32*)l, 16, 0, 0);
}
// exact GELU via A&S 7.1.26 erf approx (|eps|<=1.5e-7)
DEVFN float gelu_exact(float v) {
  float s = v * 0.70710678118654752f;
  float ax = fabsf(s);
  float t = __builtin_amdgcn_rcpf(1.0f + 0.3275911f * ax);
  float poly = t * (0.254829592f +
               t * (-0.284496736f +
               t * (1.421413741f +
               t * (-1.453152027f + t * 1.061405429f))));
  float e = __expf(-s * s);
  float er = 1.0f - poly * e;
  er = (s < 0.f) ? -er : er;
  return 0.5f * v * (1.0f + er);
}

#define VMW4() asm volatile("s_waitcnt vmcnt(4)" ::: "memory")
#define VMW2() asm volatile("s_waitcnt vmcnt(2)" ::: "memory")
#define VMW0() asm volatile("s_waitcnt vmcnt(0)" ::: "memory")
#define CFENCE() asm volatile("" ::: "memory")
#define BARRIER() do { CFENCE(); __builtin_amdgcn_s_barrier(); CFENCE(); } while (0)

// ---------------- fused: transpose+convert all 6 weights AND ln1.
// 32(k) x 128(n) tiles, float4 reads (16B/lane), LDS pad 133 (conflict-free
// transpose reads). blocks [0,4096): wq/wk/wv/wo  [4096,8192): w1
// [8192,12288): w2  [12288,16384): ln1 rows.
__global__ __launch_bounds__(256) void tconvln_k(
    const float* __restrict__ wq, const float* __restrict__ wk,
    const float* __restrict__ wv, const float* __restrict__ wo,
    const float* __restrict__ w1, const float* __restrict__ w2,
    u16* __restrict__ wqt, u16* __restrict__ wkt, u16* __restrict__ wvt,
    u16* __restrict__ wot, u16* __restrict__ w1t, u16* __restrict__ w2t,
    const float* __restrict__ x, const float* __restrict__ ln1w,
    const float* __restrict__ ln1b, float* __restrict__ y32,
    u16* __restrict__ y16) {
  int b = blockIdx.x;
  int t = threadIdx.x;
  if (b >= 12288) {  // ---- ln1 row
    long base = (long)(b - 12288) * 2048;
    float4 v0 = ((const float4*)(x + base))[2 * t];
    float4 v1 = ((const float4*)(x + base))[2 * t + 1];
    float xv[8];
    *(float4*)xv = v0; *(float4*)(xv + 4) = v1;
    float s = 0.f, ss = 0.f;
#pragma unroll
    for (int i = 0; i < 8; ++i) { s += xv[i]; ss += xv[i] * xv[i]; }
#pragma unroll
    for (int m = 1; m < 64; m <<= 1) { s += __shfl_xor(s, m); ss += __shfl_xor(ss, m); }
    __shared__ float rs[4], rss[4];
    int wave = t >> 6;
    if ((t & 63) == 0) { rs[wave] = s; rss[wave] = ss; }
    __syncthreads();
    s = rs[0] + rs[1] + rs[2] + rs[3];
    ss = rss[0] + rss[1] + rss[2] + rss[3];
    float mean = s * (1.f / 2048.f);
    float var = ss * (1.f / 2048.f) - mean * mean;
    float inv = rsqrtf(var + 1e-5f);
    float wv8[8], bv[8];
    *(float4*)wv8 = ((const float4*)ln1w)[2 * t];
    *(float4*)(wv8 + 4) = ((const float4*)ln1w)[2 * t + 1];
    *(float4*)bv = ((const float4*)ln1b)[2 * t];
    *(float4*)(bv + 4) = ((const float4*)ln1b)[2 * t + 1];
    float yv[8];
#pragma unroll
    for (int i = 0; i < 8; ++i) yv[i] = (xv[i] - mean) * inv * wv8[i] + bv[i];
    ((float4*)(y32 + base))[2 * t] = *(float4*)yv;
    ((float4*)(y32 + base))[2 * t + 1] = *(float4*)(yv + 4);
    u32x4 ov;
#pragma unroll
    for (int i = 0; i < 4; ++i) ov[i] = packbf2(yv[2 * i], yv[2 * i + 1]);
    ((u32x4*)(y16 + base))[t] = ov;
    return;
  }
  // ---- weight transpose tile (32 k-rows x 128 n-cols)
  __shared__ float tile[32][133];
  const float* in; u16* out; int K, N, tn, tk;
  if (b < 4096) {
    int wsel = b >> 10;
    int loc = b & 1023;
    in = (wsel == 0) ? wq : (wsel == 1) ? wk : (wsel == 2) ? wv : wo;
    out = (wsel == 0) ? wqt : (wsel == 1) ? wkt : (wsel == 2) ? wvt : wot;
    K = 2048; N = 2048; tn = loc & 15; tk = loc >> 4;
  } else if (b < 8192) {
    int loc = b - 4096; in = w1; out = w1t; K = 2048; N = 8192;
    tn = loc & 63; tk = loc >> 6;
  } else {
    int loc = b - 8192; in = w2; out = w2t; K = 8192; N = 2048;
    tn = loc & 15; tk = loc >> 4;
  }
  int n0 = tn << 7, k0 = tk << 5;
  int c4 = t & 31, r8 = t >> 5;
#pragma unroll
  for (int i = 0; i < 4; ++i) {
    int row = r8 + i * 8;
    float4 v = *(const float4*)(in + (long)(k0 + row) * N + n0 + c4 * 4);
    tile[row][c4 * 4 + 0] = v.x;
    tile[row][c4 * 4 + 1] = v.y;
    tile[row][c4 * 4 + 2] = v.z;
    tile[row][c4 * 4 + 3] = v.w;
  }
  __syncthreads();
  int kx = t & 31, ny = t >> 5;
#pragma unroll
  for (int j = 0; j < 16; ++j) {
    int n = ny + j * 8;
    out[(long)(n0 + n) * K + k0 + kx] = f2bf(tile[kx][n]);
  }
}

// ---------------- LayerNorm (bf16 in) -> bf16 out.
__global__ __launch_bounds__(256) void ln2_k(const u16* __restrict__ a,
                                             const float* __restrict__ w,
                                             const float* __restrict__ b,
                                             u16* __restrict__ y) {
  long base = (long)blockIdx.x * 2048;
  int t = threadIdx.x;
  u32x4 pv = ((const u32x4*)(a + base))[t];
  float xv[8];
#pragma unroll
  for (int i = 0; i < 4; ++i) {
    xv[2 * i] = bf2f((u16)(pv[i] & 0xffffu));
    xv[2 * i + 1] = bf2f((u16)(pv[i] >> 16));
  }
  float s = 0.f, ss = 0.f;
#pragma unroll
  for (int i = 0; i < 8; ++i) { s += xv[i]; ss += xv[i] * xv[i]; }
#pragma unroll
  for (int m = 1; m < 64; m <<= 1) { s += __shfl_xor(s, m); ss += __shfl_xor(ss, m); }
  __shared__ float rs[4], rss[4];
  int wave = t >> 6;
  if ((t & 63) == 0) { rs[wave] = s; rss[wave] = ss; }
  __syncthreads();
  s = rs[0] + rs[1] + rs[2] + rs[3];
  ss = rss[0] + rss[1] + rss[2] + rss[3];
  float mean = s * (1.f / 2048.f);
  float var = ss * (1.f / 2048.f) - mean * mean;
  float inv = rsqrtf(var + 1e-5f);
  float wv[8], bv[8];
  *(float4*)wv = ((const float4*)w)[2 * t]; *(float4*)(wv + 4) = ((const float4*)w)[2 * t + 1];
  *(float4*)bv = ((const float4*)b)[2 * t]; *(float4*)(bv + 4) = ((const float4*)b)[2 * t + 1];
  u32x4 ov;
#pragma unroll
  for (int i = 0; i < 4; ++i) {
    float y0 = (xv[2 * i] - mean) * inv * wv[2 * i] + bv[2 * i];
    float y1 = (xv[2 * i + 1] - mean) * inv * wv[2 * i + 1] + bv[2 * i + 1];
    ov[i] = packbf2(y0, y1);
  }
  ((u32x4*)(y + base))[t] = ov;
}

// =====================================================================
// Phase-scheduled GEMM (r3 engine — measured best: 0 conflicts).
// 512 threads = 8 waves (2M x 4N). BK=64. BN=256.
// IM=8 -> BM=256 (4 phases), IM=4 -> BM=128 (2 phases).
// MODE 0: fused QKV (W=[6144,2048]) -> q/k [B,H,S,D], v [B,H,D,S]
// MODE 2: +bias+resid(f32) -> bf16   MODE 3: +bias, exact GELU -> bf16
// MODE 4: +bias+resid(f32) -> f32
// MODE 5: w2 split-K/2 (W=[2048,8192], call K=4096) -> f32 partials
// =====================================================================
template <int MODE, int IM>
__global__ __launch_bounds__(512, 2) void gemm8_k(const u16* __restrict__ A,
                                                  const u16* __restrict__ W,
                                                  void* __restrict__ outp,
                                                  const float* __restrict__ bias,
                                                  const float* __restrict__ resid,
                                                  int M, int N, int K) {
  constexpr int BM = IM * 32;  // 256 or 128
  constexpr int BN = 256;
  __shared__ __align__(16) u16 lds[2][(BM + BN) * 64];
  const int t = threadIdx.x, lane = t & 63, wave = t >> 6;
  const int g = lane >> 4, r16 = lane & 15;
  const int wm = wave >> 2, wn = wave & 3;
  const int nM = M / BM;
  const int nwg = gridDim.x * gridDim.y;
  const int orig = blockIdx.y * gridDim.x + blockIdx.x;
  const int sw = (nwg & 7) ? orig : ((orig & 7) * (nwg >> 3) + (orig >> 3));
  const long m0 = (long)(sw % nM) * BM;
  long n0, k0;
  int ks = 0;
  if constexpr (MODE == 5) {
    int rest = sw / nM;            // 0..15
    n0 = (long)(rest & 7) * BN;
    ks = rest >> 3;
    k0 = (long)ks * 4096;
  } else {
    n0 = (long)(sw / nM) * BN;
    k0 = 0;
  }
  const int nt = K >> 6;
  const long Kl = (MODE == 5) ? 8192 : K;

  auto stA = [&](int b, int half, int tile) {
#pragma unroll
    for (int q = 0; q < 2; ++q) {
      int rl = (wave * 2 + q) * 8 + (lane >> 3);
      int c = (lane & 7) ^ (rl & 7);
      gl2lds16(A + (m0 + half * 128 + rl) * Kl + k0 + ((long)tile << 6) + c * 8,
               &lds[b][half * 8192 + (wave * 2 + q) * 512]);
    }
  };
  auto stB = [&](int b, int half, int tile) {
#pragma unroll
    for (int q = 0; q < 2; ++q) {
      int rl = (wave * 2 + q) * 8 + (lane >> 3);
      int c = (lane & 7) ^ (rl & 7);
      gl2lds16(W + (n0 + half * 128 + rl) * Kl + k0 + ((long)tile << 6) + c * 8,
               &lds[b][BM * 64 + half * 8192 + (wave * 2 + q) * 512]);
    }
  };

  f32x4 acc[IM][4] = {};
  short8 af[4][2], bf[2][2];

#define LDAF(IH)                                                              \
  _Pragma("unroll") for (int ii2 = 0; ii2 < 4; ++ii2) {                       \
    int row = (((IH)*4 + ii2) * 2 + wm) * 16 + r16;                           \
    _Pragma("unroll") for (int kk = 0; kk < 2; ++kk)                          \
        af[ii2][kk] = *(const short8*)(&lds[cur][row * 64 +                   \
                                        (((kk << 2) | g) ^ (row & 7)) * 8]);  \
  }
#define LDBF(JH)                                                              \
  _Pragma("unroll") for (int jj2 = 0; jj2 < 2; ++jj2) {                       \
    int row = (((JH)*2 + jj2) * 4 + wn) * 16 + r16;                           \
    _Pragma("unroll") for (int kk = 0; kk < 2; ++kk)                          \
        bf[jj2][kk] = *(const short8*)(&lds[cur][BM * 64 + row * 64 +         \
                                        (((kk << 2) | g) ^ (row & 7)) * 8]);  \
  }
#define MFMA_PH(IH, JH)                                                       \
  __builtin_amdgcn_s_setprio(1);                                              \
  _Pragma("unroll") for (int ii2 = 0; ii2 < 4; ++ii2)                         \
      _Pragma("unroll") for (int jj2 = 0; jj2 < 2; ++jj2)                     \
          _Pragma("unroll") for (int kk = 0; kk < 2; ++kk)                    \
              acc[(IH)*4 + ii2][(JH)*2 + jj2] =                               \
                  __builtin_amdgcn_mfma_f32_16x16x32_bf16(                    \
                      af[ii2][kk], bf[jj2][kk],                               \
                      acc[(IH)*4 + ii2][(JH)*2 + jj2], 0, 0, 0);              \
  __builtin_amdgcn_s_setprio(0);

  // prologue: stage tile 0 into buf 0 in schedule order
  if constexpr (IM == 8) {
    stA(0, 0, 0); stB(0, 0, 0); stB(0, 1, 0); stA(0, 1, 0);
    VMW4();
  } else {
    stA(0, 0, 0); stB(0, 0, 0); stB(0, 1, 0);
    VMW2();
  }
  BARRIER();

  for (int tt = 0; tt < nt; ++tt) {
    const int cur = tt & 1, nxt = cur ^ 1;
    const int ts = (tt + 1 < nt) ? tt + 1 : tt;  // clamped prefetch tile
    if constexpr (IM == 8) {
      LDAF(0); LDBF(0);
      stA(nxt, 0, ts);
      MFMA_PH(0, 0);
      VMW4(); BARRIER();
      LDBF(1);
      stB(nxt, 0, ts);
      MFMA_PH(0, 1);
      VMW4(); BARRIER();
      LDAF(1); LDBF(0);
      stB(nxt, 1, ts);
      MFMA_PH(1, 0);
      BARRIER();
      LDBF(1);
      stA(nxt, 1, ts);
      MFMA_PH(1, 1);
      VMW4(); BARRIER();
    } else {
      LDAF(0); LDBF(0);
      stA(nxt, 0, ts); stB(nxt, 0, ts);
      MFMA_PH(0, 0);
      VMW4(); BARRIER();
      LDBF(1);
      stB(nxt, 1, ts);
      MFMA_PH(0, 1);
      VMW2(); BARRIER();
    }
  }
  VMW0();

  const long Nl = N;
#pragma unroll
  for (int ii = 0; ii < IM; ++ii) {
#pragma unroll
    for (int jj = 0; jj < 4; ++jj) {
#pragma unroll
      for (int r = 0; r < 4; ++r) {
        long mg = m0 + (ii * 2 + wm) * 16 + g * 4 + r;
        long ng = n0 + (jj * 4 + wn) * 16 + r16;
        float v = acc[ii][jj][r];
        if constexpr (MODE == 0) {
          long which = ng >> 11;          // 0=q,1=k,2=v (uniform per 256-tile)
          long nloc = ng & 2047;
          long bb = mg >> 11, sq = mg & 2047;
          long hh = nloc >> 7, dd = nloc & 127;
          long idx = (which < 2) ? (((bb * 16 + hh) * 2048 + sq) * 128 + dd)
                                 : (((bb * 16 + hh) * 128 + dd) * 2048 + sq);
          ((u16*)outp)[which * 8388608 + idx] = f2bf(v);
        } else if constexpr (MODE == 2) {
          v += bias[ng] + resid[mg * Nl + ng];
          ((u16*)outp)[mg * Nl + ng] = f2bf(v);
        } else if constexpr (MODE == 3) {
          v = gelu_exact(v + bias[ng]);
          ((u16*)outp)[mg * Nl + ng] = f2bf(v);
        } else if constexpr (MODE == 5) {
          ((float*)outp)[(long)ks * 8388608 + mg * 2048 + ng] = v;
        } else {
          v += bias[ng] + resid[mg * Nl + ng];
          ((float*)outp)[mg * Nl + ng] = v;
        }
      }
    }
  }
#undef LDAF
#undef LDBF
#undef MFMA_PH
}

// ---------------- split-K reducer: out = p0 + p1 + bias + resid (all f32)
__global__ __launch_bounds__(256) void red_k(const float* __restrict__ p,
                                             const float* __restrict__ bias,
                                             const float* __restrict__ resid,
                                             float* __restrict__ out) {
  long i = (long)blockIdx.x * 256 + threadIdx.x;
  for (long idx = i; idx < 2097152; idx += 2048 * 256) {
    float4 a = ((const float4*)p)[idx];
    float4 b = ((const float4*)(p + 8388608))[idx];
    float4 r = ((const float4*)resid)[idx];
    float4 bs = ((const float4*)bias)[idx & 511];
    float4 o;
    o.x = a.x + b.x + r.x + bs.x;
    o.y = a.y + b.y + r.y + bs.y;
    o.z = a.z + b.z + r.z + bs.z;
    o.w = a.w + b.w + r.w + bs.w;
    ((float4*)out)[idx] = o;
  }
}

// =====================================================================
// Flash attention: 32x32 MFMA, swapped QK^T, in-register softmax.
// =====================================================================
__global__ __launch_bounds__(256, 2) void attn2_k(const u16* __restrict__ Qp,
                                                  const u16* __restrict__ Kp,
                                                  const u16* __restrict__ Vp,
                                                  u16* __restrict__ ctx) {
  __shared__ __align__(16) u16 KsL[2][64 * 128];
  __shared__ __align__(16) u16 VsL[2][128 * 64];
  const int qt = gridDim.x - 1 - blockIdx.x;
  const int bh = blockIdx.y;
  const int t = threadIdx.x, lane = t & 63, wave = t >> 6;
  const int l31 = lane & 31, hi = lane >> 5;
  const int q0 = qt * 128, qw0 = q0 + wave * 32;
  const int qg = qw0 + l31;
  const u16* Qh = Qp + (long)bh * 2048 * 128;
  const u16* Kh = Kp + (long)bh * 2048 * 128;
  const u16* Vh = Vp + (long)bh * 128 * 2048;
  const int nkt = qt * 2 + 2;
  const int ktmax = (qw0 + 31) >> 6;
  const float cs = 0.12753042923810058f;  // (1/sqrt(128)) * log2(e)

  short8 qf[8];
#pragma unroll
  for (int ds = 0; ds < 8; ++ds)
    qf[ds] = *(const short8*)(Qh + (long)qg * 128 + ds * 16 + hi * 8);

  f32x16 O0 = {}, O1 = {}, O2 = {}, O3 = {};
  float m = -INFINITY, l = 0.f;

  auto stage = [&](int b, int kt) {
#pragma unroll
    for (int q = 0; q < 4; ++q) {
      int r = wave * 16 + q * 4 + (lane >> 4);
      int c = (lane & 15) ^ (r & 15);
      gl2lds16(Kh + ((long)kt * 64 + r) * 128 + c * 8,
               &KsL[b][(wave * 16 + q * 4) * 128]);
    }
#pragma unroll
    for (int q = 0; q < 4; ++q) {
      int r = wave * 32 + q * 8 + (lane >> 3);
      int c = (lane & 7) ^ (r & 7);
      gl2lds16(Vh + (long)r * 2048 + kt * 64 + c * 8,
               &VsL[b][(wave * 32 + q * 8) * 64]);
    }
  };

  stage(0, 0);
  VMW0(); BARRIER();

  for (int kt = 0; kt < nkt; ++kt) {
    const int cur = kt & 1;
    if (kt + 1 < nkt) stage(cur ^ 1, kt + 1);
    if (kt <= ktmax) {
      f32x16 S0 = {}, S1 = {};
      __builtin_amdgcn_s_setprio(1);
#pragma unroll
      for (int ds = 0; ds < 8; ++ds) {
        int c0 = ((ds * 2 + hi) ^ (l31 & 15)) * 8;
        short8 k0 = *(const short8*)(&KsL[cur][l31 * 128 + c0]);
        int r1 = 32 + l31;
        int c1 = ((ds * 2 + hi) ^ (r1 & 15)) * 8;
        short8 k1 = *(const short8*)(&KsL[cur][r1 * 128 + c1]);
        S0 = __builtin_amdgcn_mfma_f32_32x32x16_bf16(k0, qf[ds], S0, 0, 0, 0);
        S1 = __builtin_amdgcn_mfma_f32_32x32x16_bf16(k1, qf[ds], S1, 0, 0, 0);
      }
      __builtin_amdgcn_s_setprio(0);
      float p[32];
#pragma unroll
      for (int i = 0; i < 16; ++i) { p[i] = S0[i]; p[16 + i] = S1[i]; }
      if (kt * 64 + 63 > qw0) {
#pragma unroll
        for (int ks = 0; ks < 2; ++ks)
#pragma unroll
          for (int r = 0; r < 16; ++r) {
            int kg = kt * 64 + ks * 32 + (r & 3) + 8 * (r >> 2) + 4 * hi;
            if (kg > qg) p[ks * 16 + r] = -INFINITY;
          }
      }
      float tmax = p[0];
#pragma unroll
      for (int i = 1; i < 32; ++i) tmax = fmaxf(tmax, p[i]);
      tmax = fmaxf(tmax, __shfl_xor(tmax, 32));
      float mnew = fmaxf(m, tmax);
      float corr = __builtin_amdgcn_exp2f((m - mnew) * cs);
      float ls = 0.f;
#pragma unroll
      for (int i = 0; i < 32; ++i) {
        p[i] = __builtin_amdgcn_exp2f((p[i] - mnew) * cs);
        ls += p[i];
      }
      ls += __shfl_xor(ls, 32);
      l = l * corr + ls;
      m = mnew;
#pragma unroll
      for (int i = 0; i < 16; ++i) {
        O0[i] *= corr; O1[i] *= corr; O2[i] *= corr; O3[i] *= corr;
      }
      short8 pf[4];
#pragma unroll
      for (int gg = 0; gg < 4; ++gg) {
        u32 u_, v_, w_, z_;
        asm("v_cvt_pk_bf16_f32 %0, %1, %2" : "=v"(u_) : "v"(p[gg * 8 + 0]), "v"(p[gg * 8 + 1]));
        asm("v_cvt_pk_bf16_f32 %0, %1, %2" : "=v"(v_) : "v"(p[gg * 8 + 2]), "v"(p[gg * 8 + 3]));
        asm("v_cvt_pk_bf16_f32 %0, %1, %2" : "=v"(w_) : "v"(p[gg * 8 + 4]), "v"(p[gg * 8 + 5]));
        asm("v_cvt_pk_bf16_f32 %0, %1, %2" : "=v"(z_) : "v"(p[gg * 8 + 6]), "v"(p[gg * 8 + 7]));
        asm("v_permlane32_swap_b32 %0, %1" : "+v"(u_), "+v"(w_));
        asm("v_permlane32_swap_b32 %0, %1" : "+v"(v_), "+v"(z_));
        union { u32 w4[4]; short8 s; } cv;
        cv.w4[0] = u_; cv.w4[1] = v_; cv.w4[2] = w_; cv.w4[3] = z_;
        pf[gg] = cv.s;
      }
      __builtin_amdgcn_s_setprio(1);
#define PVROW(ds, OO)                                                          \
  {                                                                            \
    int row = (ds)*32 + l31;                                                   \
    _Pragma("unroll") for (int gg = 0; gg < 4; ++gg) {                         \
      short8 vf = *(const short8*)(&VsL[cur][row * 64 +                        \
                                             (((gg * 2 + hi) ^ (row & 7)) * 8)]); \
      OO = __builtin_amdgcn_mfma_f32_32x32x16_bf16(vf, pf[gg], OO, 0, 0, 0);   \
    }                                                                          \
  }
      PVROW(0, O0); PVROW(1, O1); PVROW(2, O2); PVROW(3, O3);
#undef PVROW
      __builtin_amdgcn_s_setprio(0);
    }
    VMW0(); BARRIER();
  }

  const float inv = 1.f / l;
  u16* cp = ctx + ((long)(bh >> 4) * 2048 + qg) * 2048 + (bh & 15) * 128;
#define WROUT(OO, dsb)                                                         \
  _Pragma("unroll") for (int rg = 0; rg < 4; ++rg) {                           \
    int d = (dsb)*32 + 8 * rg + 4 * hi;                                        \
    u32x2 wv;                                                                  \
    wv[0] = packbf2(OO[4 * rg] * inv, OO[4 * rg + 1] * inv);                   \
    wv[1] = packbf2(OO[4 * rg + 2] * inv, OO[4 * rg + 3] * inv);               \
    *(u32x2*)(cp + d) = wv;                                                    \
  }
  WROUT(O0, 0); WROUT(O1, 1); WROUT(O2, 2); WROUT(O3, 3);
#undef WROUT
}

extern "C" void kernel_launch(void* const* d_in, const int* in_sizes, int n_in,
                              void* d_out, int out_size, void* d_ws, size_t ws_size,
                              hipStream_t stream) {
  const float* x = (const float*)d_in[0];
  const float* ln1w = (const float*)d_in[1];
  const float* ln1b = (const float*)d_in[2];
  const float* wq = (const float*)d_in[3];
  const float* wk = (const float*)d_in[4];
  const float* wv = (const float*)d_in[5];
  const float* wo = (const float*)d_in[6];
  const float* bo = (const float*)d_in[7];
  const float* ln2w = (const float*)d_in[8];
  const float* ln2b = (const float*)d_in[9];
  const float* w1 = (const float*)d_in[10];
  const float* b1 = (const float*)d_in[11];
  const float* w2 = (const float*)d_in[12];
  const float* b2 = (const float*)d_in[13];
  float* out = (float*)d_out;
  char* ws = (char*)d_ws;

  float* x1f = (float*)(ws + 0);            // 33,554,432 B (x1 fp32, w2 resid)
  u16* x1b = (u16*)(ws + 33554432);         // 16,777,216
  u16* wqt = (u16*)(ws + 50331648);         //  8,388,608 (wq/wk/wv contiguous = [6144,2048])
  u16* wkt = (u16*)(ws + 58720256);
  u16* wvt = (u16*)(ws + 67108864);
  u16* wot = (u16*)(ws + 75497472);
  u16* w1t = (u16*)(ws + 83886080);         // 33,554,432
  u16* w2t = (u16*)(ws + 117440512);        // 33,554,432
  u16* qb = (u16*)(ws + 150994944);         // 16,777,216 (q/k/v contiguous)
  u16* kb = (u16*)(ws + 167772160);
  u16* vb = (u16*)(ws + 184549376);
  u16* ctxb = (u16*)(ws + 201326592);
  u16* ab = (u16*)(ws + 218103808);
  u16* y0b = (u16*)(ws + 234881024);        // ends 251,658,240
  u16* hb = qb;                              // 64 MB alias over q/k/v/ctx
  float* pbuf = (float*)(ws + 50331648);     // 64 MB split-K partials
                                             // (wqt..w1t dead by w2 time)

  tconvln_k<<<16384, 256, 0, stream>>>(wq, wk, wv, wo, w1, w2,
                                       wqt, wkt, wvt, wot, w1t, w2t,
                                       x, ln1w, ln1b, x1f, x1b);
  gemm8_k<0, 8><<<dim3(16, 24), 512, 0, stream>>>(x1b, wqt, qb, nullptr, nullptr, 4096, 6144, 2048);
  attn2_k<<<dim3(16, 32), 256, 0, stream>>>(qb, kb, vb, ctxb);
  gemm8_k<2, 4><<<dim3(32, 8), 512, 0, stream>>>(ctxb, wot, ab, bo, x, 4096, 2048, 2048);
  ln2_k<<<4096, 256, 0, stream>>>(ab, ln2w, ln2b, y0b);
  gemm8_k<3, 8><<<dim3(16, 32), 512, 0, stream>>>(y0b, w1t, hb, b1, nullptr, 4096, 8192, 2048);
  gemm8_k<5, 8><<<dim3(16, 16), 512, 0, stream>>>(hb, w2t, pbuf, nullptr, nullptr, 4096, 2048, 4096);
  red_k<<<2048, 256, 0, stream>>>(pbuf, b2, x1f, out);
}